// Round 12
// baseline (238.868 us; speedup 1.0000x reference)
//
#include <hip/hip_runtime.h>

#define SEQ   4096
#define HH    4
#define SCALE 0.125f
// exp2-folded constants: p' = exp2(s*SC2 + C16), SC2 = SCALE*log2(e) folded
// into Q at projection (wq,bq pre-scaled). Column softmax (axis=1 = i):
// Z_j = sum_i p'_ij; normalizer folded into V ONCE (k_vnorm: u_j = v_j/Z_j),
// so attnpv's inner loop has NO per-j bias: out_i = sum_j p'_ij u_j.
#define SC2   0.18033688011112042f
#define C16   -23.083120654223414f   /* -16*log2(e), overflow guard */

typedef __bf16 bf16x8 __attribute__((ext_vector_type(8)));
typedef __bf16 bf16x4 __attribute__((ext_vector_type(4)));
typedef float  f32x4  __attribute__((ext_vector_type(4)));

// ---- ws layout (float offsets) ----
// Q frag-packed: [bh][tile16][frag2][512] (Q pre-scaled by SC2);
// K frag-packed with PERMUTED rows: [bh][jc32][tile2][frag2][512],
//   tile row m <-> j = (m>>2)*8 + t*4 + (m&3) so S^T = mfma(K,Q) lands
//   directly in the PV B-fragment layout (no cross-lane redistribution).
// V: [bh][jc32][nd4][512]  (normalized in place by k_vnorm).
constexpr size_t OFF_W16  = 0;         // 4x65536 bf16 weights (wq slab pre-scaled by SC2)
constexpr size_t OFF_A    = 131072;    // [bh*S+j] r_j = 1/Z_j (fp32)
constexpr size_t OFF_AO   = 294912;    // [8192][256] fp32 attn out (atomic)
constexpr size_t OFF_X16  = 9732096;   // 6291456 bf16 (x cast)
constexpr size_t OFF_Q16  = 12877824;  // packed Q,K,V bf16 regions
constexpr size_t K16OFF   = 2097152;
constexpr size_t V16OFF   = 4194304;
constexpr size_t OFF_PZ   = 16023552;  // [16][32768] colstats partials

__device__ __forceinline__ f32x4 mf(bf16x8 a, bf16x8 b, f32x4 c) {
    return __builtin_amdgcn_mfma_f32_16x16x32_bf16(a, b, c, 0, 0, 0);
}

__device__ __forceinline__ float ex2(float x) {
    return __builtin_amdgcn_exp2f(x);
}

// ---- prep: cast x, cast weights (wq pre-scaled by SC2), zero AO ----
__global__ void k_prep(const float* __restrict__ x,
                       const float* __restrict__ wq, const float* __restrict__ wk,
                       const float* __restrict__ wv, const float* __restrict__ wo,
                       float* __restrict__ ws) {
    int bx = blockIdx.x, t = threadIdx.x;
    if (bx < 6144) {
        size_t i4 = ((size_t)bx * 256 + t) * 4;
        float4 v = *(const float4*)(x + i4);
        bf16x4 o = {(__bf16)v.x, (__bf16)v.y, (__bf16)v.z, (__bf16)v.w};
        *(bf16x4*)((__bf16*)(ws + OFF_X16) + i4) = o;
    } else if (bx < 6400) {
        int q = bx - 6144;
        int y = q >> 6;
        const float* src = (y == 0) ? wq : (y == 1) ? wk : (y == 2) ? wv : wo;
        float sc = (y == 0) ? SC2 : 1.0f;
        size_t i4 = ((size_t)(q & 63) * 256 + t) * 4;
        float4 v = *(const float4*)(src + i4);
        bf16x4 o = {(__bf16)(v.x * sc), (__bf16)(v.y * sc),
                    (__bf16)(v.z * sc), (__bf16)(v.w * sc)};
        *(bf16x4*)((__bf16*)(ws + OFF_W16) + (size_t)y * 65536 + i4) = o;
    } else {
        size_t i4 = ((size_t)(bx - 6400) * 256 + t) * 4;
        *(float4*)(ws + OFF_AO + i4) = make_float4(0.f, 0.f, 0.f, 0.f);
    }
}

// ---- QKV projection; grid (128, 3, 2): z splits the 256-col output ----
__global__ __launch_bounds__(256) void k_qkv_mfma(const float* __restrict__ bq,
                                                  const float* __restrict__ bk,
                                                  const float* __restrict__ bv,
                                                  float* __restrict__ ws) {
    int t = threadIdx.x, lane = t & 63, w = t >> 6;
    int yw = blockIdx.y;
    int ntb = blockIdx.z * 8;
    int row0 = blockIdx.x * 64 + w * 16;
    int mrow = lane & 15, quad = lane >> 4;
    const __bf16* X16 = (const __bf16*)(ws + OFF_X16);
    const __bf16* W16 = (const __bf16*)(ws + OFF_W16) + (size_t)yw * 65536;
    const float* bias = (yw == 0) ? bq : (yw == 1) ? bk : bv;
    __bf16* Qb = (__bf16*)(ws + OFF_Q16);
    f32x4 acc[8];
#pragma unroll
    for (int n = 0; n < 8; n++) acc[n] = {0.f, 0.f, 0.f, 0.f};
    const __bf16* ap = X16 + (size_t)(row0 + mrow) * 768 + yw * 256 + quad * 8;
    const __bf16* bp = W16 + (size_t)ntb * 4096 + (size_t)mrow * 256 + quad * 8;
    for (int kc = 0; kc < 256; kc += 32) {
        bf16x8 a = *(const bf16x8*)(ap + kc);
#pragma unroll
        for (int nt = 0; nt < 8; nt++) {
            bf16x8 b = *(const bf16x8*)(bp + (size_t)nt * 4096 + kc);
            acc[nt] = mf(a, b, acc[nt]);
        }
    }
#pragma unroll
    for (int nt = 0; nt < 8; nt++) {
        int n = (ntb + nt) * 16 + mrow;
        float bb = bias[n];
        if (yw == 0) bb *= SC2;
        int h = n >> 6, d = n & 63;
#pragma unroll
        for (int r = 0; r < 4; r++) {
            int sg = row0 + quad * 4 + r;
            int b_ = sg >> 12, s = sg & 4095;
            int bh = b_ * HH + h;
            float val = acc[nt][r] + bb;
            if (yw == 0) {
                int tile = s >> 4, m = s & 15, frag = d >> 5, q2 = (d >> 3) & 3, e = d & 7;
                size_t idx = (((size_t)bh * 256 + tile) * 2 + frag) * 512 +
                             (size_t)(q2 * 16 + m) * 8 + e;
                Qb[idx] = (__bf16)val;
            } else if (yw == 1) {
                int jc = s >> 5, jj = s & 31;
                int tl = (jj >> 2) & 1, m = ((jj >> 3) << 2) | (jj & 3);
                int frag = d >> 5, q2 = (d >> 3) & 3, e = d & 7;
                size_t idx = (((size_t)bh * 128 + jc) * 4 + tl * 2 + frag) * 512 +
                             (size_t)(q2 * 16 + m) * 8 + e;
                Qb[K16OFF + idx] = (__bf16)val;
            } else {
                int jc = s >> 5, qk = (s >> 3) & 3, e = s & 7;
                int nd = d >> 4, nl = d & 15;
                size_t idx = (((size_t)bh * 128 + jc) * 4 + nd) * 512 +
                             (size_t)(qk * 16 + nl) * 8 + e;
                Qb[V16OFF + idx] = (__bf16)val;
            }
        }
    }
}

// ---- pass 1: Z_j partials; 64 j/wave (8 K frags), BARRIER-FREE ----
// grid (16 jb, 16 iy, 8 bh) = 2048 blocks; NO LDS: Q frags loaded directly
// from global (L2/L3-resident, perfectly coalesced 1KB per load); waves are
// fully independent and self-paced.
__global__ __launch_bounds__(256, 4) void k_colstats(float* __restrict__ ws) {
    int t = threadIdx.x, lane = t & 63, w = t >> 6;
    int jb = blockIdx.x, iy = blockIdx.y, bh = blockIdx.z;
    int jc0 = jb * 8 + w * 2;          // two 32-j chunks per wave
    const __bf16* Qp = (const __bf16*)(ws + OFF_Q16);
    const __bf16* Kp = Qp + K16OFF;
    const __bf16* kb = Kp + ((size_t)(bh * 128 + jc0) * 4) * 512 + lane * 8;
    bf16x8 kA0 = *(const bf16x8*)(kb);
    bf16x8 kA1 = *(const bf16x8*)(kb + 512);
    bf16x8 kB0 = *(const bf16x8*)(kb + 1024);
    bf16x8 kB1 = *(const bf16x8*)(kb + 1536);
    bf16x8 kC0 = *(const bf16x8*)(kb + 2048);
    bf16x8 kC1 = *(const bf16x8*)(kb + 2560);
    bf16x8 kD0 = *(const bf16x8*)(kb + 3072);
    bf16x8 kD1 = *(const bf16x8*)(kb + 3584);
    const __bf16* qg = Qp + ((size_t)(bh * 256 + iy * 16) * 2) * 512 + lane * 8;
    const f32x4 cin = {C16, C16, C16, C16};
    float z0 = 0.f, z1 = 0.f, z2 = 0.f, z3 = 0.f;
    for (int tt = 0; tt < 16; tt++) {
        bf16x8 a0 = *(const bf16x8*)(qg);
        bf16x8 a1 = *(const bf16x8*)(qg + 512);
        qg += 1024;
        f32x4 cA = mf(a0, kA0, cin); cA = mf(a1, kA1, cA);
        f32x4 cB = mf(a0, kB0, cin); cB = mf(a1, kB1, cB);
        f32x4 cC = mf(a0, kC0, cin); cC = mf(a1, kC1, cC);
        f32x4 cD = mf(a0, kD0, cin); cD = mf(a1, kD1, cD);
#pragma unroll
        for (int r = 0; r < 4; r++) {
            z0 += ex2(cA[r]);
            z1 += ex2(cB[r]);
            z2 += ex2(cC[r]);
            z3 += ex2(cD[r]);
        }
    }
    z0 += __shfl_xor(z0, 16, 64);
    z0 += __shfl_xor(z0, 32, 64);
    z1 += __shfl_xor(z1, 16, 64);
    z1 += __shfl_xor(z1, 32, 64);
    z2 += __shfl_xor(z2, 16, 64);
    z2 += __shfl_xor(z2, 32, 64);
    z3 += __shfl_xor(z3, 16, 64);
    z3 += __shfl_xor(z3, 32, 64);
    if (lane < 16) {
        // col m of tile t in chunk c -> j = (jc0+c)*32 + (m>>2)*8 + t*4 + (m&3)
        size_t o = OFF_PZ + (size_t)iy * 32768 + (size_t)bh * SEQ +
                   jc0 * 32 + ((lane >> 2) << 3) + (lane & 3);
        ws[o] = z0;
        ws[o + 4] = z1;
        ws[o + 32] = z2;
        ws[o + 36] = z3;
    }
}

// ---- pass 1b: r_j = 1 / (sum of partials) ----
__global__ void k_afin(float* __restrict__ ws) {
    int idx = blockIdx.x * 256 + threadIdx.x;
    const float* pz = ws + OFF_PZ;
    float Z = 0.f;
#pragma unroll
    for (int y = 0; y < 16; y++) Z += pz[(size_t)y * 32768 + idx];
    ws[OFF_A + idx] = 1.0f / Z;
}

// ---- pass 1c: V <- V * r_j (in place); 1024 blocks x 256 thr x 8 elems ----
__global__ void k_vnorm(float* __restrict__ ws) {
    int f = blockIdx.x * 256 + threadIdx.x;      // 262144 threads
    __bf16* V = (__bf16*)(ws + OFF_Q16) + V16OFF;
    const float* R = ws + OFF_A;
    size_t base = (size_t)f * 8;
    int c = f >> 6;                // 512-elem chunk index
    int p0 = (int)(base & 511);
    int bh = c >> 9, jc = (c >> 2) & 127;
    int qk = p0 >> 7;
    int jb = jc * 32 + qk * 8;     // 8 consecutive j for e=0..7
    const float* r = R + (size_t)bh * SEQ + jb;
    bf16x8 v = *(const bf16x8*)(V + base);
    f32x4 r0 = *(const f32x4*)(r);
    f32x4 r1 = *(const f32x4*)(r + 4);
    bf16x8 o;
#pragma unroll
    for (int e = 0; e < 4; e++) {
        o[e]     = (__bf16)((float)v[e] * r0[e]);
        o[4 + e] = (__bf16)((float)v[4 + e] * r1[e]);
    }
    *(bf16x8*)(V + base) = o;
}

// ---- pass 2: BARRIER-FREE fused attention. 32 i/wave, 1024 j/wave (32 jt);
// NO LDS staging: K/V fragments loaded per-wave directly from global
// (L2/L3-resident, 1KB coalesced loads), single-reg-set reload-after-use
// software pipeline (K reloaded mid-phase, V at phase end -> ~1 phase of
// latency slack each; compiler emits counted vmcnt, no barrier drains).
// grid (32,4,8) = 1024 blocks -> 16 waves/CU (launch_bounds pins VGPR<=128).
__global__ __launch_bounds__(256, 4) void k_attnpv(float* __restrict__ ws) {
    __shared__ float sO[4][1040];            // per-wave epilogue transpose
    int t = threadIdx.x, lane = t & 63, w = t >> 6;
    int jy = blockIdx.y, bh = blockIdx.z;    // jy: 1024-j slab
    int itp = blockIdx.x * 4 + w;            // 0..127
    int it0 = itp * 2;                       // two 16-row Q tiles
    int mrow = lane & 15, quad = lane >> 4;
    const __bf16* Qp = (const __bf16*)(ws + OFF_Q16);
    const __bf16* Kp = Qp + K16OFF;
    const __bf16* Vp = Qp + V16OFF;

    const __bf16* qb = Qp + ((size_t)(bh * 256 + it0) * 2) * 512 + lane * 8;
    bf16x8 aq00 = *(const bf16x8*)(qb);
    bf16x8 aq01 = *(const bf16x8*)(qb + 512);
    bf16x8 aq10 = *(const bf16x8*)(qb + 1024);
    bf16x8 aq11 = *(const bf16x8*)(qb + 1536);

    f32x4 oT0[4], oT1[4];
#pragma unroll
    for (int nd = 0; nd < 4; nd++) {
        oT0[nd] = {0.f, 0.f, 0.f, 0.f};
        oT1[nd] = {0.f, 0.f, 0.f, 0.f};
    }
    const f32x4 cin = {C16, C16, C16, C16};
    int c0g = jy * 32;                       // first 32-j chunk of this slab
    const __bf16* kg = Kp + ((size_t)(bh * 128 + c0g) * 4) * 512 + lane * 8;
    const __bf16* vg = Vp + ((size_t)(bh * 128 + c0g) * 4) * 512 + lane * 8;
    bf16x8 k0 = *(const bf16x8*)(kg);
    bf16x8 k1 = *(const bf16x8*)(kg + 512);
    bf16x8 k2 = *(const bf16x8*)(kg + 1024);
    bf16x8 k3 = *(const bf16x8*)(kg + 1536);
    bf16x8 v0 = *(const bf16x8*)(vg);
    bf16x8 v1 = *(const bf16x8*)(vg + 512);
    bf16x8 v2 = *(const bf16x8*)(vg + 1024);
    bf16x8 v3 = *(const bf16x8*)(vg + 1536);
    kg += 2048; vg += 2048;

    for (int jt = 0; jt < 32; ++jt) {
        // A-half: S^T rows for q-tile it0
        f32x4 c00 = mf(k0, aq00, cin); c00 = mf(k1, aq01, c00);
        f32x4 c01 = mf(k2, aq00, cin); c01 = mf(k3, aq01, c01);
        bf16x8 pb0;
#pragma unroll
        for (int r = 0; r < 4; r++) {
            pb0[r]     = (__bf16)ex2(c00[r]);
            pb0[4 + r] = (__bf16)ex2(c01[r]);
        }
        oT0[0] = mf(v0, pb0, oT0[0]);
        oT0[1] = mf(v1, pb0, oT0[1]);
        oT0[2] = mf(v2, pb0, oT0[2]);
        oT0[3] = mf(v3, pb0, oT0[3]);
        // B-half: q-tile it0+1 (K regs last used here, then reloaded)
        f32x4 c10 = mf(k0, aq10, cin); c10 = mf(k1, aq11, c10);
        f32x4 c11 = mf(k2, aq10, cin); c11 = mf(k3, aq11, c11);
        if (jt < 31) {
            k0 = *(const bf16x8*)(kg);
            k1 = *(const bf16x8*)(kg + 512);
            k2 = *(const bf16x8*)(kg + 1024);
            k3 = *(const bf16x8*)(kg + 1536);
            kg += 2048;
        }
        bf16x8 pb1;
#pragma unroll
        for (int r = 0; r < 4; r++) {
            pb1[r]     = (__bf16)ex2(c10[r]);
            pb1[4 + r] = (__bf16)ex2(c11[r]);
        }
        oT1[0] = mf(v0, pb1, oT1[0]);
        oT1[1] = mf(v1, pb1, oT1[1]);
        oT1[2] = mf(v2, pb1, oT1[2]);
        oT1[3] = mf(v3, pb1, oT1[3]);
        if (jt < 31) {
            v0 = *(const bf16x8*)(vg);
            v1 = *(const bf16x8*)(vg + 512);
            v2 = *(const bf16x8*)(vg + 1024);
            v3 = *(const bf16x8*)(vg + 1536);
            vg += 2048;
        }
    }

    // epilogue: wave-PRIVATE LDS transpose (no barriers), coalesced atomics
    float* so = sO[w];
    int b = bh >> 2, h = bh & 3;
    float* AO = ws + OFF_AO;
    int i0 = it0 * 16;
#pragma unroll
    for (int nd = 0; nd < 4; nd++)
#pragma unroll
        for (int r = 0; r < 4; r++)
            so[mrow * 65 + nd * 16 + quad * 4 + r] = oT0[nd][r];
#pragma unroll
    for (int c = 0; c < 16; c++)
        atomicAdd(&AO[((size_t)(b * SEQ + i0 + c)) * 256 + h * 64 + lane],
                  so[c * 65 + lane]);
#pragma unroll
    for (int nd = 0; nd < 4; nd++)
#pragma unroll
        for (int r = 0; r < 4; r++)
            so[mrow * 65 + nd * 16 + quad * 4 + r] = oT1[nd][r];
#pragma unroll
    for (int c = 0; c < 16; c++)
        atomicAdd(&AO[((size_t)(b * SEQ + i0 + 16 + c)) * 256 + h * 64 + lane],
                  so[c * 65 + lane]);
}

// ---- output projection; grid (128, 4): y splits cols -> 512 blocks ----
__global__ __launch_bounds__(256) void k_outproj_mfma(const float* __restrict__ bo,
                                                      float* __restrict__ ws,
                                                      float* __restrict__ out) {
    int t = threadIdx.x, lane = t & 63, w = t >> 6;
    int row0 = blockIdx.x * 64 + w * 16;
    int ntb = blockIdx.y * 4;
    int mrow = lane & 15, quad = lane >> 4;
    const float* AO = ws + OFF_AO;
    const __bf16* W16 = (const __bf16*)(ws + OFF_W16) + (size_t)3 * 65536;
    f32x4 acc[4];
#pragma unroll
    for (int n = 0; n < 4; n++) acc[n] = {0.f, 0.f, 0.f, 0.f};
    const float* ap = AO + (size_t)(row0 + mrow) * 256 + quad * 8;
    const __bf16* bp = W16 + (size_t)ntb * 4096 + (size_t)mrow * 256 + quad * 8;
    for (int kc = 0; kc < 256; kc += 32) {
        float4 u = *(const float4*)(ap + kc);
        float4 v = *(const float4*)(ap + kc + 4);
        bf16x8 a = {(__bf16)u.x, (__bf16)u.y, (__bf16)u.z, (__bf16)u.w,
                    (__bf16)v.x, (__bf16)v.y, (__bf16)v.z, (__bf16)v.w};
#pragma unroll
        for (int nt = 0; nt < 4; nt++) {
            bf16x8 b = *(const bf16x8*)(bp + (size_t)nt * 4096 + kc);
            acc[nt] = mf(a, b, acc[nt]);
        }
    }
#pragma unroll
    for (int nt = 0; nt < 4; nt++) {
        int n = (ntb + nt) * 16 + mrow;
        float bb = bo[n];
#pragma unroll
        for (int r = 0; r < 4; r++) {
            int sg = row0 + quad * 4 + r;
            out[(size_t)sg * 256 + n] = acc[nt][r] + bb;
        }
    }
}

extern "C" void kernel_launch(void* const* d_in, const int* in_sizes, int n_in,
                              void* d_out, int out_size, void* d_ws, size_t ws_size,
                              hipStream_t stream) {
    const float* x  = (const float*)d_in[0];
    const float* wq = (const float*)d_in[1];
    const float* bq = (const float*)d_in[2];
    const float* wk = (const float*)d_in[3];
    const float* bk = (const float*)d_in[4];
    const float* wv = (const float*)d_in[5];
    const float* bv = (const float*)d_in[6];
    const float* wo = (const float*)d_in[7];
    const float* bo = (const float*)d_in[8];
    float* ws = (float*)d_ws;
    float* out = (float*)d_out;

    k_prep<<<8448, 256, 0, stream>>>(x, wq, wk, wv, wo, ws);
    k_qkv_mfma<<<dim3(128, 3, 2), 256, 0, stream>>>(bq, bk, bv, ws);
    k_colstats<<<dim3(16, 16, 8), 256, 0, stream>>>(ws);
    k_afin<<<128, 256, 0, stream>>>(ws);
    k_vnorm<<<1024, 256, 0, stream>>>(ws);
    k_attnpv<<<dim3(32, 4, 8), 256, 0, stream>>>(ws);
    k_outproj_mfma<<<dim3(128, 4), 256, 0, stream>>>(bo, ws, out);
}

// Round 13
// 198.827 us; speedup vs baseline: 1.2014x; 1.2014x over previous
//
#include <hip/hip_runtime.h>

#define SEQ   4096
#define HH    4
#define SCALE 0.125f
// exp2-folded constants: p = exp2(s*SC2 + a2), SC2 = SCALE*log2(e).
// SC2 folded into Q at projection (wq,bq pre-scaled); a2_j rides in the MFMA
// C-initializer. Softmax normalizes over i (axis=1): stats pass computes
// COLUMN sums Z_j = sum_i exp2(s'_ij + C16).
#define SC2   0.18033688011112042f
#define C16   -23.083120654223414f   /* -16*log2(e) */

typedef __bf16 bf16x8 __attribute__((ext_vector_type(8)));
typedef __bf16 bf16x4 __attribute__((ext_vector_type(4)));
typedef float  f32x4  __attribute__((ext_vector_type(4)));

// ---- ws layout (float offsets) ----
constexpr size_t OFF_W16  = 0;         // 4x65536 bf16 weights (wq slab pre-scaled by SC2)
constexpr size_t OFF_A    = 131072;    // [bh*S+j] a2_j = C16 - log2(Z_j)
constexpr size_t OFF_AO   = 294912;    // [8192][256] fp32 attn out (atomic)
constexpr size_t OFF_X16  = 9732096;   // 6291456 bf16 (x cast)
constexpr size_t OFF_Q16  = 12877824;  // packed Q,K,V bf16 regions
constexpr size_t K16OFF   = 2097152;
constexpr size_t V16OFF   = 4194304;
constexpr size_t OFF_PZ   = 16023552;  // [16][32768] colstats partials

__device__ __forceinline__ f32x4 mf(bf16x8 a, bf16x8 b, f32x4 c) {
    return __builtin_amdgcn_mfma_f32_16x16x32_bf16(a, b, c, 0, 0, 0);
}

__device__ __forceinline__ void gload16(const __bf16* g, __bf16* l) {
    __builtin_amdgcn_global_load_lds(
        (const __attribute__((address_space(1))) unsigned int*)g,
        (__attribute__((address_space(3))) unsigned int*)l, 16, 0, 0);
}

__device__ __forceinline__ float ex2(float x) {
    return __builtin_amdgcn_exp2f(x);
}

// ---- prep: cast x, cast weights (wq pre-scaled by SC2), zero AO ----
__global__ void k_prep(const float* __restrict__ x,
                       const float* __restrict__ wq, const float* __restrict__ wk,
                       const float* __restrict__ wv, const float* __restrict__ wo,
                       float* __restrict__ ws) {
    int bx = blockIdx.x, t = threadIdx.x;
    if (bx < 6144) {
        size_t i4 = ((size_t)bx * 256 + t) * 4;
        float4 v = *(const float4*)(x + i4);
        bf16x4 o = {(__bf16)v.x, (__bf16)v.y, (__bf16)v.z, (__bf16)v.w};
        *(bf16x4*)((__bf16*)(ws + OFF_X16) + i4) = o;
    } else if (bx < 6400) {
        int q = bx - 6144;
        int y = q >> 6;
        const float* src = (y == 0) ? wq : (y == 1) ? wk : (y == 2) ? wv : wo;
        float sc = (y == 0) ? SC2 : 1.0f;
        size_t i4 = ((size_t)(q & 63) * 256 + t) * 4;
        float4 v = *(const float4*)(src + i4);
        bf16x4 o = {(__bf16)(v.x * sc), (__bf16)(v.y * sc),
                    (__bf16)(v.z * sc), (__bf16)(v.w * sc)};
        *(bf16x4*)((__bf16*)(ws + OFF_W16) + (size_t)y * 65536 + i4) = o;
    } else {
        size_t i4 = ((size_t)(bx - 6400) * 256 + t) * 4;
        *(float4*)(ws + OFF_AO + i4) = make_float4(0.f, 0.f, 0.f, 0.f);
    }
}

// ---- QKV projection; grid (128, 3, 2). NEW: wave-private LDS dest-image
// epilogue -> coalesced 16B stores (replaces 32 scattered 2B stores/thread).
__global__ __launch_bounds__(256) void k_qkv_mfma(const float* __restrict__ bq,
                                                  const float* __restrict__ bk,
                                                  const float* __restrict__ bv,
                                                  float* __restrict__ ws) {
    __shared__ __bf16 sbuf[4][2][1024];      // [wave][head][dest-image]
    int t = threadIdx.x, lane = t & 63, w = t >> 6;
    int yw = blockIdx.y;
    int ntb = blockIdx.z * 8;
    int row0 = blockIdx.x * 64 + w * 16;
    int mrow = lane & 15, quad = lane >> 4;
    const __bf16* X16 = (const __bf16*)(ws + OFF_X16);
    const __bf16* W16 = (const __bf16*)(ws + OFF_W16) + (size_t)yw * 65536;
    const float* bias = (yw == 0) ? bq : (yw == 1) ? bk : bv;
    __bf16* Qb = (__bf16*)(ws + OFF_Q16);
    f32x4 acc[8];
#pragma unroll
    for (int n = 0; n < 8; n++) acc[n] = {0.f, 0.f, 0.f, 0.f};
    const __bf16* ap = X16 + (size_t)(row0 + mrow) * 768 + yw * 256 + quad * 8;
    const __bf16* bp = W16 + (size_t)ntb * 4096 + (size_t)mrow * 256 + quad * 8;
    for (int kc = 0; kc < 256; kc += 32) {
        bf16x8 a = *(const bf16x8*)(ap + kc);
#pragma unroll
        for (int nt = 0; nt < 8; nt++) {
            bf16x8 b = *(const bf16x8*)(bp + (size_t)nt * 4096 + kc);
            acc[nt] = mf(a, b, acc[nt]);
        }
    }
    // ---- epilogue ----
    int T = blockIdx.x * 4 + w;              // global 16-row tile id
    int b_ = T >> 8, Ts = T & 255;           // batch, tile-within-seq
    int th = Ts & 1;
    // stage: acc -> wave-private LDS dest-image (no barriers needed)
#pragma unroll
    for (int nt = 0; nt < 8; nt++) {
        int hsel = nt >> 2, c4 = nt & 3;
        int n = (ntb + nt) * 16 + mrow;
        float bb = bias[n];
        if (yw == 0) bb *= SC2;
        __bf16* sb = &sbuf[w][hsel][0];
#pragma unroll
        for (int r = 0; r < 4; r++) {
            float val = acc[nt][r] + bb;
            int loff;
            if (yw == 0) {
                int q2 = ((c4 & 1) << 1) | (mrow >> 3);
                loff = (c4 >> 1) * 512 + (q2 * 16 + quad * 4 + r) * 8 + (mrow & 7);
            } else if (yw == 1) {
                int q2 = ((c4 & 1) << 1) | (mrow >> 3);
                int piece = ((quad & 1) * 2 + (c4 >> 1)) * 4 + q2;
                loff = piece * 64 + ((quad >> 1) * 4 + r) * 8 + (mrow & 7);
            } else {
                loff = c4 * 256 + (quad >> 1) * 128 + mrow * 8 + (quad & 1) * 4 + r;
            }
            sb[loff] = (__bf16)val;
        }
    }
    // coalesced stores: 2 heads x 2 rounds x 16B per lane
#pragma unroll
    for (int hsel = 0; hsel < 2; hsel++) {
        int h = blockIdx.z * 2 + hsel;
        int bh = b_ * HH + h;
        const __bf16* sb = &sbuf[w][hsel][0];
#pragma unroll
        for (int rd = 0; rd < 2; rd++) {
            int g = rd * 64 + lane;
            bf16x8 vv = *(const bf16x8*)(sb + g * 8);
            size_t gaddr;
            if (yw == 0) {
                gaddr = (((size_t)bh * 256 + Ts) * 2) * 512 + (size_t)g * 8;
            } else if (yw == 1) {
                int p = g >> 3;
                gaddr = K16OFF + (((size_t)bh * 128 + (Ts >> 1)) * 4 + (p >> 2)) * 512
                        + (size_t)((p & 3) * 128 + th * 64 + (g & 7) * 8);
            } else {
                int p = g >> 4;
                gaddr = V16OFF + (((size_t)bh * 128 + (Ts >> 1)) * 4 + (p >> 1)) * 512
                        + (size_t)((th * 2 + (p & 1)) * 128 + (g & 15) * 8);
            }
            *(bf16x8*)(Qb + gaddr) = vv;
        }
    }
}

// ---- pass 1: Z_j partials; 64 j/wave (8 K frags), 256 i/block ----
// grid (16 jb, 16 iy, 8 bh) = 2048 blocks; Q staged 64-i chunks dbuf'd. (R8)
__global__ __launch_bounds__(256) void k_colstats(float* __restrict__ ws) {
    __shared__ __bf16 qbuf[2][4096];
    int t = threadIdx.x, lane = t & 63, w = t >> 6;
    int jb = blockIdx.x, iy = blockIdx.y, bh = blockIdx.z;
    int jc0 = jb * 8 + w * 2;          // two 32-j chunks per wave
    const __bf16* Qp = (const __bf16*)(ws + OFF_Q16);
    const __bf16* Kp = Qp + K16OFF;
    const __bf16* kb = Kp + ((size_t)(bh * 128 + jc0) * 4) * 512 + lane * 8;
    bf16x8 kA0 = *(const bf16x8*)(kb);
    bf16x8 kA1 = *(const bf16x8*)(kb + 512);
    bf16x8 kB0 = *(const bf16x8*)(kb + 1024);
    bf16x8 kB1 = *(const bf16x8*)(kb + 1536);
    bf16x8 kC0 = *(const bf16x8*)(kb + 2048);
    bf16x8 kC1 = *(const bf16x8*)(kb + 2560);
    bf16x8 kD0 = *(const bf16x8*)(kb + 3072);
    bf16x8 kD1 = *(const bf16x8*)(kb + 3584);
    const __bf16* q0 = Qp + ((size_t)(bh * 256 + iy * 16) * 2) * 512 +
                       w * 1024 + lane * 8;
    gload16(q0, qbuf[0] + w * 1024);
    gload16(q0 + 512, qbuf[0] + w * 1024 + 512);
    __syncthreads();
    const f32x4 cin = {C16, C16, C16, C16};
    float z0 = 0.f, z1 = 0.f, z2 = 0.f, z3 = 0.f;
    for (int ic = 0; ic < 4; ic++) {
        const __bf16* cur = qbuf[ic & 1];
        if (ic < 3) {
            const __bf16* qn = Qp + ((size_t)(bh * 256 + iy * 16 + (ic + 1) * 4) * 2) * 512 +
                               w * 1024 + lane * 8;
            gload16(qn, qbuf[(ic + 1) & 1] + w * 1024);
            gload16(qn + 512, qbuf[(ic + 1) & 1] + w * 1024 + 512);
        }
#pragma unroll
        for (int it = 0; it < 4; it++) {
            bf16x8 a0 = *(const bf16x8*)(cur + it * 1024 + lane * 8);
            bf16x8 a1 = *(const bf16x8*)(cur + it * 1024 + 512 + lane * 8);
            f32x4 cA = mf(a0, kA0, cin); cA = mf(a1, kA1, cA);
            f32x4 cB = mf(a0, kB0, cin); cB = mf(a1, kB1, cB);
            f32x4 cC = mf(a0, kC0, cin); cC = mf(a1, kC1, cC);
            f32x4 cD = mf(a0, kD0, cin); cD = mf(a1, kD1, cD);
#pragma unroll
            for (int r = 0; r < 4; r++) {
                z0 += ex2(cA[r]);
                z1 += ex2(cB[r]);
                z2 += ex2(cC[r]);
                z3 += ex2(cD[r]);
            }
        }
        __syncthreads();
    }
    z0 += __shfl_xor(z0, 16, 64);
    z0 += __shfl_xor(z0, 32, 64);
    z1 += __shfl_xor(z1, 16, 64);
    z1 += __shfl_xor(z1, 32, 64);
    z2 += __shfl_xor(z2, 16, 64);
    z2 += __shfl_xor(z2, 32, 64);
    z3 += __shfl_xor(z3, 16, 64);
    z3 += __shfl_xor(z3, 32, 64);
    if (lane < 16) {
        size_t o = OFF_PZ + (size_t)iy * 32768 + (size_t)bh * SEQ +
                   jc0 * 32 + ((lane >> 2) << 3) + (lane & 3);
        ws[o] = z0;
        ws[o + 4] = z1;
        ws[o + 32] = z2;
        ws[o + 36] = z3;
    }
}

// ---- pass 1b: a2_j = C16 - log2(sum of partials) ----
__global__ void k_afin(float* __restrict__ ws) {
    int idx = blockIdx.x * 256 + threadIdx.x;
    const float* pz = ws + OFF_PZ;
    float Z = 0.f;
#pragma unroll
    for (int y = 0; y < 16; y++) Z += pz[(size_t)y * 32768 + idx];
    ws[OFF_A + idx] = C16 - __log2f(Z);
}

// ---- pass 2 (R8 best): 32 i/wave, 1024 j/block (32 jt); 3-buffer K/V
// pipeline, counted vmcnt(2), raw s_barrier; a2 slab in LDS.
// NEW: s_setprio(1) around the two MFMA clusters (T5). grid (32,4,8). ----
__global__ __launch_bounds__(256) void k_attnpv(float* __restrict__ ws) {
    __shared__ __align__(16) char pool[28672];
    float* sA = (float*)(pool + 24576);      // [1024] a2 for this j-slab
    int t = threadIdx.x, lane = t & 63, w = t >> 6;
    int jy = blockIdx.y, bh = blockIdx.z;
    int itp = blockIdx.x * 4 + w;
    int it0 = itp * 2;
    int mrow = lane & 15, quad = lane >> 4;
    const __bf16* Qp = (const __bf16*)(ws + OFF_Q16);
    const __bf16* Kp = Qp + K16OFF;
    const __bf16* Vp = Qp + V16OFF;

    {
        const float* Ag = ws + OFF_A + (size_t)bh * SEQ + jy * 1024;
        *(float4*)(sA + t * 4) = *(const float4*)(Ag + t * 4);
    }
    const __bf16* qb = Qp + ((size_t)(bh * 256 + it0) * 2) * 512 + lane * 8;
    bf16x8 aq00 = *(const bf16x8*)(qb);
    bf16x8 aq01 = *(const bf16x8*)(qb + 512);
    bf16x8 aq10 = *(const bf16x8*)(qb + 1024);
    bf16x8 aq11 = *(const bf16x8*)(qb + 1536);

    f32x4 oT0[4], oT1[4];
#pragma unroll
    for (int nd = 0; nd < 4; nd++) {
        oT0[nd] = {0.f, 0.f, 0.f, 0.f};
        oT1[nd] = {0.f, 0.f, 0.f, 0.f};
    }
    int c0g = jy * 32;
    const __bf16* kg = Kp + ((size_t)(bh * 128 + c0g) * 4) * 512 + w * 512 + lane * 8;
    const __bf16* vg = Vp + ((size_t)(bh * 128 + c0g) * 4) * 512 + w * 512 + lane * 8;
    gload16(kg, (__bf16*)pool + w * 512);
    gload16(vg, (__bf16*)(pool + 4096) + w * 512);
    kg += 2048; vg += 2048;
    __syncthreads();

    int bc = 0;
    for (int jt = 0; jt < 32; ++jt) {
        int bn = (bc == 2) ? 0 : bc + 1;
        if (jt < 31) {
            gload16(kg, (__bf16*)(pool + bn * 8192) + w * 512);
            gload16(vg, (__bf16*)(pool + bn * 8192 + 4096) + w * 512);
            kg += 2048; vg += 2048;
            asm volatile("s_waitcnt vmcnt(2)" ::: "memory");
        } else {
            asm volatile("s_waitcnt vmcnt(0)" ::: "memory");
        }
        __builtin_amdgcn_s_barrier();
        const __bf16* curK = (const __bf16*)(pool + bc * 8192);
        const __bf16* curV = (const __bf16*)(pool + bc * 8192 + 4096);
        f32x4 aL = *(const f32x4*)(sA + jt * 32 + quad * 8);
        f32x4 aH = *(const f32x4*)(sA + jt * 32 + quad * 8 + 4);
        bf16x8 ck0 = *(const bf16x8*)(curK + lane * 8);
        bf16x8 ck1 = *(const bf16x8*)(curK + 512 + lane * 8);
        bf16x8 ck2 = *(const bf16x8*)(curK + 1024 + lane * 8);
        bf16x8 ck3 = *(const bf16x8*)(curK + 1536 + lane * 8);
        __builtin_amdgcn_s_setprio(1);
        f32x4 c00 = mf(ck0, aq00, aL); c00 = mf(ck1, aq01, c00);
        f32x4 c01 = mf(ck2, aq00, aH); c01 = mf(ck3, aq01, c01);
        f32x4 c10 = mf(ck0, aq10, aL); c10 = mf(ck1, aq11, c10);
        f32x4 c11 = mf(ck2, aq10, aH); c11 = mf(ck3, aq11, c11);
        __builtin_amdgcn_s_setprio(0);
        bf16x8 pb0, pb1;
#pragma unroll
        for (int r = 0; r < 4; r++) {
            pb0[r]     = (__bf16)ex2(c00[r]);
            pb0[4 + r] = (__bf16)ex2(c01[r]);
            pb1[r]     = (__bf16)ex2(c10[r]);
            pb1[4 + r] = (__bf16)ex2(c11[r]);
        }
        __builtin_amdgcn_s_setprio(1);
#pragma unroll
        for (int nd = 0; nd < 4; nd++) {
            bf16x8 bv = *(const bf16x8*)(curV + nd * 512 + lane * 8);
            oT0[nd] = mf(bv, pb0, oT0[nd]);
            oT1[nd] = mf(bv, pb1, oT1[nd]);
        }
        __builtin_amdgcn_s_setprio(0);
        bc = bn;
    }
    __syncthreads();

    float* sO = (float*)pool + (size_t)w * 1040;
    int b = bh >> 2, h = bh & 3;
    float* AO = ws + OFF_AO;
    int i0 = it0 * 16;
#pragma unroll
    for (int nd = 0; nd < 4; nd++)
#pragma unroll
        for (int r = 0; r < 4; r++)
            sO[mrow * 65 + nd * 16 + quad * 4 + r] = oT0[nd][r];
#pragma unroll
    for (int c = 0; c < 16; c++)
        atomicAdd(&AO[((size_t)(b * SEQ + i0 + c)) * 256 + h * 64 + lane],
                  sO[c * 65 + lane]);
#pragma unroll
    for (int nd = 0; nd < 4; nd++)
#pragma unroll
        for (int r = 0; r < 4; r++)
            sO[mrow * 65 + nd * 16 + quad * 4 + r] = oT1[nd][r];
#pragma unroll
    for (int c = 0; c < 16; c++)
        atomicAdd(&AO[((size_t)(b * SEQ + i0 + 16 + c)) * 256 + h * 64 + lane],
                  sO[c * 65 + lane]);
}

// ---- output projection; grid (128, 4): y splits cols -> 512 blocks ----
__global__ __launch_bounds__(256) void k_outproj_mfma(const float* __restrict__ bo,
                                                      float* __restrict__ ws,
                                                      float* __restrict__ out) {
    int t = threadIdx.x, lane = t & 63, w = t >> 6;
    int row0 = blockIdx.x * 64 + w * 16;
    int ntb = blockIdx.y * 4;
    int mrow = lane & 15, quad = lane >> 4;
    const float* AO = ws + OFF_AO;
    const __bf16* W16 = (const __bf16*)(ws + OFF_W16) + (size_t)3 * 65536;
    f32x4 acc[4];
#pragma unroll
    for (int n = 0; n < 4; n++) acc[n] = {0.f, 0.f, 0.f, 0.f};
    const float* ap = AO + (size_t)(row0 + mrow) * 256 + quad * 8;
    const __bf16* bp = W16 + (size_t)ntb * 4096 + (size_t)mrow * 256 + quad * 8;
    for (int kc = 0; kc < 256; kc += 32) {
        float4 u = *(const float4*)(ap + kc);
        float4 v = *(const float4*)(ap + kc + 4);
        bf16x8 a = {(__bf16)u.x, (__bf16)u.y, (__bf16)u.z, (__bf16)u.w,
                    (__bf16)v.x, (__bf16)v.y, (__bf16)v.z, (__bf16)v.w};
#pragma unroll
        for (int nt = 0; nt < 4; nt++) {
            bf16x8 b = *(const bf16x8*)(bp + (size_t)nt * 4096 + kc);
            acc[nt] = mf(a, b, acc[nt]);
        }
    }
#pragma unroll
    for (int nt = 0; nt < 4; nt++) {
        int n = (ntb + nt) * 16 + mrow;
        float bb = bo[n];
#pragma unroll
        for (int r = 0; r < 4; r++) {
            int sg = row0 + quad * 4 + r;
            out[(size_t)sg * 256 + n] = acc[nt][r] + bb;
        }
    }
}

extern "C" void kernel_launch(void* const* d_in, const int* in_sizes, int n_in,
                              void* d_out, int out_size, void* d_ws, size_t ws_size,
                              hipStream_t stream) {
    const float* x  = (const float*)d_in[0];
    const float* wq = (const float*)d_in[1];
    const float* bq = (const float*)d_in[2];
    const float* wk = (const float*)d_in[3];
    const float* bk = (const float*)d_in[4];
    const float* wv = (const float*)d_in[5];
    const float* bv = (const float*)d_in[6];
    const float* wo = (const float*)d_in[7];
    const float* bo = (const float*)d_in[8];
    float* ws = (float*)d_ws;
    float* out = (float*)d_out;

    k_prep<<<8448, 256, 0, stream>>>(x, wq, wk, wv, wo, ws);
    k_qkv_mfma<<<dim3(128, 3, 2), 256, 0, stream>>>(bq, bk, bv, ws);
    k_colstats<<<dim3(16, 16, 8), 256, 0, stream>>>(ws);
    k_afin<<<128, 256, 0, stream>>>(ws);
    k_attnpv<<<dim3(32, 4, 8), 256, 0, stream>>>(ws);
    k_outproj_mfma<<<dim3(128, 4), 256, 0, stream>>>(bo, ws, out);
}

// Round 14
// 198.285 us; speedup vs baseline: 1.2047x; 1.0027x over previous
//
#include <hip/hip_runtime.h>

#define SEQ   4096
#define HH    4
#define SCALE 0.125f
// exp2-folded constants: p = exp2(s*SC2 + a2), SC2 = SCALE*log2(e).
// SC2 folded into Q at projection (wq,bq pre-scaled); a2_j = C16 - log2(Z_j)
// rides in the MFMA C-initializer (computed in attnpv's sA staging from the
// atomically-accumulated Z). Softmax normalizes over i (axis=1): colstats
// computes COLUMN sums Z_j = sum_i exp2(s'_ij + C16) straight into OFF_A.
#define SC2   0.18033688011112042f
#define C16   -23.083120654223414f   /* -16*log2(e) */

typedef __bf16 bf16x8 __attribute__((ext_vector_type(8)));
typedef __bf16 bf16x4 __attribute__((ext_vector_type(4)));
typedef float  f32x4  __attribute__((ext_vector_type(4)));

// ---- ws layout (float offsets) ----
constexpr size_t OFF_W16  = 0;         // 4x65536 bf16 weights (wq slab pre-scaled by SC2)
constexpr size_t OFF_A    = 131072;    // [bh*S+j] Z_j (atomic), read as a2 by attnpv
constexpr size_t OFF_AO   = 294912;    // [8192][256] fp32 attn out (atomic)
constexpr size_t OFF_X16  = 9732096;   // 6291456 bf16 (x cast)
constexpr size_t OFF_Q16  = 12877824;  // packed Q,K,V bf16 regions
constexpr size_t K16OFF   = 2097152;
constexpr size_t V16OFF   = 4194304;

__device__ __forceinline__ f32x4 mf(bf16x8 a, bf16x8 b, f32x4 c) {
    return __builtin_amdgcn_mfma_f32_16x16x32_bf16(a, b, c, 0, 0, 0);
}

__device__ __forceinline__ void gload16(const __bf16* g, __bf16* l) {
    __builtin_amdgcn_global_load_lds(
        (const __attribute__((address_space(1))) unsigned int*)g,
        (__attribute__((address_space(3))) unsigned int*)l, 16, 0, 0);
}

__device__ __forceinline__ float ex2(float x) {
    return __builtin_amdgcn_exp2f(x);
}

// ---- prep: cast x, cast weights (wq pre-scaled by SC2), zero AO + Z ----
__global__ void k_prep(const float* __restrict__ x,
                       const float* __restrict__ wq, const float* __restrict__ wk,
                       const float* __restrict__ wv, const float* __restrict__ wo,
                       float* __restrict__ ws) {
    int bx = blockIdx.x, t = threadIdx.x;
    if (bx < 6144) {
        size_t i4 = ((size_t)bx * 256 + t) * 4;
        float4 v = *(const float4*)(x + i4);
        bf16x4 o = {(__bf16)v.x, (__bf16)v.y, (__bf16)v.z, (__bf16)v.w};
        *(bf16x4*)((__bf16*)(ws + OFF_X16) + i4) = o;
    } else if (bx < 6400) {
        int q = bx - 6144;
        int y = q >> 6;
        const float* src = (y == 0) ? wq : (y == 1) ? wk : (y == 2) ? wv : wo;
        float sc = (y == 0) ? SC2 : 1.0f;
        size_t i4 = ((size_t)(q & 63) * 256 + t) * 4;
        float4 v = *(const float4*)(src + i4);
        bf16x4 o = {(__bf16)(v.x * sc), (__bf16)(v.y * sc),
                    (__bf16)(v.z * sc), (__bf16)(v.w * sc)};
        *(bf16x4*)((__bf16*)(ws + OFF_W16) + (size_t)y * 65536 + i4) = o;
    } else if (bx < 8448) {
        size_t i4 = ((size_t)(bx - 6400) * 256 + t) * 4;
        *(float4*)(ws + OFF_AO + i4) = make_float4(0.f, 0.f, 0.f, 0.f);
    } else {
        size_t i4 = ((size_t)(bx - 8448) * 256 + t) * 4;
        *(float4*)(ws + OFF_A + i4) = make_float4(0.f, 0.f, 0.f, 0.f);
    }
}

// ---- QKV projection; grid (128, 3, 2); LDS dest-image coalesced epilogue ----
__global__ __launch_bounds__(256) void k_qkv_mfma(const float* __restrict__ bq,
                                                  const float* __restrict__ bk,
                                                  const float* __restrict__ bv,
                                                  float* __restrict__ ws) {
    __shared__ __bf16 sbuf[4][2][1024];      // [wave][head][dest-image]
    int t = threadIdx.x, lane = t & 63, w = t >> 6;
    int yw = blockIdx.y;
    int ntb = blockIdx.z * 8;
    int row0 = blockIdx.x * 64 + w * 16;
    int mrow = lane & 15, quad = lane >> 4;
    const __bf16* X16 = (const __bf16*)(ws + OFF_X16);
    const __bf16* W16 = (const __bf16*)(ws + OFF_W16) + (size_t)yw * 65536;
    const float* bias = (yw == 0) ? bq : (yw == 1) ? bk : bv;
    __bf16* Qb = (__bf16*)(ws + OFF_Q16);
    f32x4 acc[8];
#pragma unroll
    for (int n = 0; n < 8; n++) acc[n] = {0.f, 0.f, 0.f, 0.f};
    const __bf16* ap = X16 + (size_t)(row0 + mrow) * 768 + yw * 256 + quad * 8;
    const __bf16* bp = W16 + (size_t)ntb * 4096 + (size_t)mrow * 256 + quad * 8;
    for (int kc = 0; kc < 256; kc += 32) {
        bf16x8 a = *(const bf16x8*)(ap + kc);
#pragma unroll
        for (int nt = 0; nt < 8; nt++) {
            bf16x8 b = *(const bf16x8*)(bp + (size_t)nt * 4096 + kc);
            acc[nt] = mf(a, b, acc[nt]);
        }
    }
    // ---- epilogue ----
    int T = blockIdx.x * 4 + w;              // global 16-row tile id
    int b_ = T >> 8, Ts = T & 255;           // batch, tile-within-seq
    int th = Ts & 1;
#pragma unroll
    for (int nt = 0; nt < 8; nt++) {
        int hsel = nt >> 2, c4 = nt & 3;
        int n = (ntb + nt) * 16 + mrow;
        float bb = bias[n];
        if (yw == 0) bb *= SC2;
        __bf16* sb = &sbuf[w][hsel][0];
#pragma unroll
        for (int r = 0; r < 4; r++) {
            float val = acc[nt][r] + bb;
            int loff;
            if (yw == 0) {
                int q2 = ((c4 & 1) << 1) | (mrow >> 3);
                loff = (c4 >> 1) * 512 + (q2 * 16 + quad * 4 + r) * 8 + (mrow & 7);
            } else if (yw == 1) {
                int q2 = ((c4 & 1) << 1) | (mrow >> 3);
                int piece = ((quad & 1) * 2 + (c4 >> 1)) * 4 + q2;
                loff = piece * 64 + ((quad >> 1) * 4 + r) * 8 + (mrow & 7);
            } else {
                loff = c4 * 256 + (quad >> 1) * 128 + mrow * 8 + (quad & 1) * 4 + r;
            }
            sb[loff] = (__bf16)val;
        }
    }
#pragma unroll
    for (int hsel = 0; hsel < 2; hsel++) {
        int h = blockIdx.z * 2 + hsel;
        int bh = b_ * HH + h;
        const __bf16* sb = &sbuf[w][hsel][0];
#pragma unroll
        for (int rd = 0; rd < 2; rd++) {
            int g = rd * 64 + lane;
            bf16x8 vv = *(const bf16x8*)(sb + g * 8);
            size_t gaddr;
            if (yw == 0) {
                gaddr = (((size_t)bh * 256 + Ts) * 2) * 512 + (size_t)g * 8;
            } else if (yw == 1) {
                int p = g >> 3;
                gaddr = K16OFF + (((size_t)bh * 128 + (Ts >> 1)) * 4 + (p >> 2)) * 512
                        + (size_t)((p & 3) * 128 + th * 64 + (g & 7) * 8);
            } else {
                int p = g >> 4;
                gaddr = V16OFF + (((size_t)bh * 128 + (Ts >> 1)) * 4 + (p >> 1)) * 512
                        + (size_t)((th * 2 + (p & 1)) * 128 + (g & 15) * 8);
            }
            *(bf16x8*)(Qb + gaddr) = vv;
        }
    }
}

// ---- pass 1: Z_j; 64 j/wave (8 K frags); 3-buffer counted-vmcnt pipeline
// (2-tile 4KB chunks, vmcnt(1), raw s_barrier, setprio); Z accumulated
// atomically into OFF_A (afin fused away). grid (16,16,8), LDS 12KB. ----
__global__ __launch_bounds__(256) void k_colstats(float* __restrict__ ws) {
    __shared__ __bf16 qbuf[3][2048];
    int t = threadIdx.x, lane = t & 63, w = t >> 6;
    int jb = blockIdx.x, iy = blockIdx.y, bh = blockIdx.z;
    int jc0 = jb * 8 + w * 2;          // two 32-j chunks per wave
    const __bf16* Qp = (const __bf16*)(ws + OFF_Q16);
    const __bf16* Kp = Qp + K16OFF;
    const __bf16* kb = Kp + ((size_t)(bh * 128 + jc0) * 4) * 512 + lane * 8;
    bf16x8 kA0 = *(const bf16x8*)(kb);
    bf16x8 kA1 = *(const bf16x8*)(kb + 512);
    bf16x8 kB0 = *(const bf16x8*)(kb + 1024);
    bf16x8 kB1 = *(const bf16x8*)(kb + 1536);
    bf16x8 kC0 = *(const bf16x8*)(kb + 2048);
    bf16x8 kC1 = *(const bf16x8*)(kb + 2560);
    bf16x8 kD0 = *(const bf16x8*)(kb + 3072);
    bf16x8 kD1 = *(const bf16x8*)(kb + 3584);
    // Q chunks: 2 tiles (32 i) = 4KB; wave stages its 1KB quarter
    const __bf16* qg = Qp + ((size_t)(bh * 256 + iy * 16) * 2) * 512 +
                       w * 512 + lane * 8;
    gload16(qg, qbuf[0] + w * 512);
    qg += 2048;
    __syncthreads();
    const f32x4 cin = {C16, C16, C16, C16};
    float z0 = 0.f, z1 = 0.f, z2 = 0.f, z3 = 0.f;
    int bc = 0;
    for (int ic = 0; ic < 8; ic++) {
        int bn = (bc == 2) ? 0 : bc + 1;
        if (ic < 7) {
            gload16(qg, qbuf[bn] + w * 512);
            qg += 2048;
            asm volatile("s_waitcnt vmcnt(1)" ::: "memory");
        } else {
            asm volatile("s_waitcnt vmcnt(0)" ::: "memory");
        }
        __builtin_amdgcn_s_barrier();
        const __bf16* cur = qbuf[bc];
#pragma unroll
        for (int it = 0; it < 2; it++) {
            bf16x8 a0 = *(const bf16x8*)(cur + it * 1024 + lane * 8);
            bf16x8 a1 = *(const bf16x8*)(cur + it * 1024 + 512 + lane * 8);
            __builtin_amdgcn_s_setprio(1);
            f32x4 cA = mf(a0, kA0, cin); cA = mf(a1, kA1, cA);
            f32x4 cB = mf(a0, kB0, cin); cB = mf(a1, kB1, cB);
            f32x4 cC = mf(a0, kC0, cin); cC = mf(a1, kC1, cC);
            f32x4 cD = mf(a0, kD0, cin); cD = mf(a1, kD1, cD);
            __builtin_amdgcn_s_setprio(0);
#pragma unroll
            for (int r = 0; r < 4; r++) {
                z0 += ex2(cA[r]);
                z1 += ex2(cB[r]);
                z2 += ex2(cC[r]);
                z3 += ex2(cD[r]);
            }
        }
        bc = bn;
    }
    z0 += __shfl_xor(z0, 16, 64);
    z0 += __shfl_xor(z0, 32, 64);
    z1 += __shfl_xor(z1, 16, 64);
    z1 += __shfl_xor(z1, 32, 64);
    z2 += __shfl_xor(z2, 16, 64);
    z2 += __shfl_xor(z2, 32, 64);
    z3 += __shfl_xor(z3, 16, 64);
    z3 += __shfl_xor(z3, 32, 64);
    if (lane < 16) {
        // col m of tile t in chunk c -> j = (jc0+c)*32 + (m>>2)*8 + t*4 + (m&3)
        float* Zp = ws + OFF_A + (size_t)bh * SEQ +
                    jc0 * 32 + ((lane >> 2) << 3) + (lane & 3);
        atomicAdd(Zp, z0);
        atomicAdd(Zp + 4, z1);
        atomicAdd(Zp + 32, z2);
        atomicAdd(Zp + 36, z3);
    }
}

// ---- pass 2 (R13 best): 32 i/wave, 1024 j/block (32 jt); 3-buffer K/V
// pipeline, counted vmcnt(2), raw s_barrier, setprio; a2 computed from Z
// during sA staging. grid (32,4,8). ----
__global__ __launch_bounds__(256) void k_attnpv(float* __restrict__ ws) {
    __shared__ __align__(16) char pool[28672];
    float* sA = (float*)(pool + 24576);      // [1024] a2 for this j-slab
    int t = threadIdx.x, lane = t & 63, w = t >> 6;
    int jy = blockIdx.y, bh = blockIdx.z;
    int itp = blockIdx.x * 4 + w;
    int it0 = itp * 2;
    int mrow = lane & 15, quad = lane >> 4;
    const __bf16* Qp = (const __bf16*)(ws + OFF_Q16);
    const __bf16* Kp = Qp + K16OFF;
    const __bf16* Vp = Qp + V16OFF;

    {
        const float* Zg = ws + OFF_A + (size_t)bh * SEQ + jy * 1024;
        float4 zv = *(const float4*)(Zg + t * 4);
        float4 av = make_float4(C16 - __log2f(zv.x), C16 - __log2f(zv.y),
                                C16 - __log2f(zv.z), C16 - __log2f(zv.w));
        *(float4*)(sA + t * 4) = av;
    }
    const __bf16* qb = Qp + ((size_t)(bh * 256 + it0) * 2) * 512 + lane * 8;
    bf16x8 aq00 = *(const bf16x8*)(qb);
    bf16x8 aq01 = *(const bf16x8*)(qb + 512);
    bf16x8 aq10 = *(const bf16x8*)(qb + 1024);
    bf16x8 aq11 = *(const bf16x8*)(qb + 1536);

    f32x4 oT0[4], oT1[4];
#pragma unroll
    for (int nd = 0; nd < 4; nd++) {
        oT0[nd] = {0.f, 0.f, 0.f, 0.f};
        oT1[nd] = {0.f, 0.f, 0.f, 0.f};
    }
    int c0g = jy * 32;
    const __bf16* kg = Kp + ((size_t)(bh * 128 + c0g) * 4) * 512 + w * 512 + lane * 8;
    const __bf16* vg = Vp + ((size_t)(bh * 128 + c0g) * 4) * 512 + w * 512 + lane * 8;
    gload16(kg, (__bf16*)pool + w * 512);
    gload16(vg, (__bf16*)(pool + 4096) + w * 512);
    kg += 2048; vg += 2048;
    __syncthreads();

    int bc = 0;
    for (int jt = 0; jt < 32; ++jt) {
        int bn = (bc == 2) ? 0 : bc + 1;
        if (jt < 31) {
            gload16(kg, (__bf16*)(pool + bn * 8192) + w * 512);
            gload16(vg, (__bf16*)(pool + bn * 8192 + 4096) + w * 512);
            kg += 2048; vg += 2048;
            asm volatile("s_waitcnt vmcnt(2)" ::: "memory");
        } else {
            asm volatile("s_waitcnt vmcnt(0)" ::: "memory");
        }
        __builtin_amdgcn_s_barrier();
        const __bf16* curK = (const __bf16*)(pool + bc * 8192);
        const __bf16* curV = (const __bf16*)(pool + bc * 8192 + 4096);
        f32x4 aL = *(const f32x4*)(sA + jt * 32 + quad * 8);
        f32x4 aH = *(const f32x4*)(sA + jt * 32 + quad * 8 + 4);
        bf16x8 ck0 = *(const bf16x8*)(curK + lane * 8);
        bf16x8 ck1 = *(const bf16x8*)(curK + 512 + lane * 8);
        bf16x8 ck2 = *(const bf16x8*)(curK + 1024 + lane * 8);
        bf16x8 ck3 = *(const bf16x8*)(curK + 1536 + lane * 8);
        __builtin_amdgcn_s_setprio(1);
        f32x4 c00 = mf(ck0, aq00, aL); c00 = mf(ck1, aq01, c00);
        f32x4 c01 = mf(ck2, aq00, aH); c01 = mf(ck3, aq01, c01);
        f32x4 c10 = mf(ck0, aq10, aL); c10 = mf(ck1, aq11, c10);
        f32x4 c11 = mf(ck2, aq10, aH); c11 = mf(ck3, aq11, c11);
        __builtin_amdgcn_s_setprio(0);
        bf16x8 pb0, pb1;
#pragma unroll
        for (int r = 0; r < 4; r++) {
            pb0[r]     = (__bf16)ex2(c00[r]);
            pb0[4 + r] = (__bf16)ex2(c01[r]);
            pb1[r]     = (__bf16)ex2(c10[r]);
            pb1[4 + r] = (__bf16)ex2(c11[r]);
        }
        __builtin_amdgcn_s_setprio(1);
#pragma unroll
        for (int nd = 0; nd < 4; nd++) {
            bf16x8 bv = *(const bf16x8*)(curV + nd * 512 + lane * 8);
            oT0[nd] = mf(bv, pb0, oT0[nd]);
            oT1[nd] = mf(bv, pb1, oT1[nd]);
        }
        __builtin_amdgcn_s_setprio(0);
        bc = bn;
    }
    __syncthreads();

    float* sO = (float*)pool + (size_t)w * 1040;
    int b = bh >> 2, h = bh & 3;
    float* AO = ws + OFF_AO;
    int i0 = it0 * 16;
#pragma unroll
    for (int nd = 0; nd < 4; nd++)
#pragma unroll
        for (int r = 0; r < 4; r++)
            sO[mrow * 65 + nd * 16 + quad * 4 + r] = oT0[nd][r];
#pragma unroll
    for (int c = 0; c < 16; c++)
        atomicAdd(&AO[((size_t)(b * SEQ + i0 + c)) * 256 + h * 64 + lane],
                  sO[c * 65 + lane]);
#pragma unroll
    for (int nd = 0; nd < 4; nd++)
#pragma unroll
        for (int r = 0; r < 4; r++)
            sO[mrow * 65 + nd * 16 + quad * 4 + r] = oT1[nd][r];
#pragma unroll
    for (int c = 0; c < 16; c++)
        atomicAdd(&AO[((size_t)(b * SEQ + i0 + 16 + c)) * 256 + h * 64 + lane],
                  sO[c * 65 + lane]);
}

// ---- output projection; grid (128, 4): y splits cols -> 512 blocks ----
__global__ __launch_bounds__(256) void k_outproj_mfma(const float* __restrict__ bo,
                                                      float* __restrict__ ws,
                                                      float* __restrict__ out) {
    int t = threadIdx.x, lane = t & 63, w = t >> 6;
    int row0 = blockIdx.x * 64 + w * 16;
    int ntb = blockIdx.y * 4;
    int mrow = lane & 15, quad = lane >> 4;
    const float* AO = ws + OFF_AO;
    const __bf16* W16 = (const __bf16*)(ws + OFF_W16) + (size_t)3 * 65536;
    f32x4 acc[4];
#pragma unroll
    for (int n = 0; n < 4; n++) acc[n] = {0.f, 0.f, 0.f, 0.f};
    const float* ap = AO + (size_t)(row0 + mrow) * 256 + quad * 8;
    const __bf16* bp = W16 + (size_t)ntb * 4096 + (size_t)mrow * 256 + quad * 8;
    for (int kc = 0; kc < 256; kc += 32) {
        float4 u = *(const float4*)(ap + kc);
        float4 v = *(const float4*)(ap + kc + 4);
        bf16x8 a = {(__bf16)u.x, (__bf16)u.y, (__bf16)u.z, (__bf16)u.w,
                    (__bf16)v.x, (__bf16)v.y, (__bf16)v.z, (__bf16)v.w};
#pragma unroll
        for (int nt = 0; nt < 4; nt++) {
            bf16x8 b = *(const bf16x8*)(bp + (size_t)nt * 4096 + kc);
            acc[nt] = mf(a, b, acc[nt]);
        }
    }
#pragma unroll
    for (int nt = 0; nt < 4; nt++) {
        int n = (ntb + nt) * 16 + mrow;
        float bb = bo[n];
#pragma unroll
        for (int r = 0; r < 4; r++) {
            int sg = row0 + quad * 4 + r;
            out[(size_t)sg * 256 + n] = acc[nt][r] + bb;
        }
    }
}

extern "C" void kernel_launch(void* const* d_in, const int* in_sizes, int n_in,
                              void* d_out, int out_size, void* d_ws, size_t ws_size,
                              hipStream_t stream) {
    const float* x  = (const float*)d_in[0];
    const float* wq = (const float*)d_in[1];
    const float* bq = (const float*)d_in[2];
    const float* wk = (const float*)d_in[3];
    const float* bk = (const float*)d_in[4];
    const float* wv = (const float*)d_in[5];
    const float* bv = (const float*)d_in[6];
    const float* wo = (const float*)d_in[7];
    const float* bo = (const float*)d_in[8];
    float* ws = (float*)d_ws;
    float* out = (float*)d_out;

    k_prep<<<8480, 256, 0, stream>>>(x, wq, wk, wv, wo, ws);
    k_qkv_mfma<<<dim3(128, 3, 2), 256, 0, stream>>>(bq, bk, bv, ws);
    k_colstats<<<dim3(16, 16, 8), 256, 0, stream>>>(ws);
    k_attnpv<<<dim3(32, 4, 8), 256, 0, stream>>>(ws);
    k_outproj_mfma<<<dim3(128, 4), 256, 0, stream>>>(bo, ws, out);
}